// Round 1
// baseline (101.771 us; speedup 1.0000x reference)
//
#include <hip/hip_runtime.h>

#define NPTS 8192
#define NB 2

// Initialize output to +FLT_MAX bit pattern so atomicMin(uint) works.
// (Harness zeroes d_out before the correctness launch and poisons 0xAA before
// timed launches -- we must init ourselves, every call.)
__global__ void _chamfer_init(unsigned int* __restrict__ o) {
    o[blockIdx.x * 256 + threadIdx.x] = 0x7F7FFFFFu; // bits of FLT_MAX
}

// dir = blockIdx.z >> 4 : 0 -> dl (a=x, b=y), 1 -> dr (a=y, b=x)
// chunk = blockIdx.z & 15 : which 512-point slice of b this block scans
// Each block: 1024 a-points (4 per thread), one 512-point b-chunk in LDS.
__global__ __launch_bounds__(256) void _chamfer_min(const float* __restrict__ x,
                                                    const float* __restrict__ y,
                                                    unsigned int* __restrict__ out) {
    const int atile = blockIdx.x;       // 0..7
    const int batch = blockIdx.y;       // 0..1
    const int dir   = blockIdx.z >> 4;  // 0..1
    const int chunk = blockIdx.z & 15;  // 0..15

    const float* a = dir ? y : x;
    const float* b = dir ? x : y;
    unsigned int* o = out + dir * (NB * NPTS) + batch * NPTS;

    __shared__ float lds[512 * 3];

    // Stage b-chunk: 512 points = 1536 floats = 384 float4 (16B-aligned:
    // offsets are multiples of 1536 floats from a 256B-aligned base).
    {
        const float4* bsrc = (const float4*)(b + batch * NPTS * 3 + chunk * 512 * 3);
        float4* l4 = (float4*)lds;
        for (int t = threadIdx.x; t < 384; t += 256) l4[t] = bsrc[t];
    }

    // Each thread owns 4 consecutive a-points: 12 floats = 3 aligned float4.
    const int pbase = atile * 1024 + threadIdx.x * 4;
    float ax0,ay0,az0, ax1,ay1,az1, ax2,ay2,az2, ax3,ay3,az3;
    {
        const float4* asrc = (const float4*)(a + batch * NPTS * 3 + pbase * 3);
        float4 q0 = asrc[0], q1 = asrc[1], q2 = asrc[2];
        ax0=q0.x; ay0=q0.y; az0=q0.z;
        ax1=q0.w; ay1=q1.x; az1=q1.y;
        ax2=q1.z; ay2=q1.w; az2=q2.x;
        ax3=q2.y; ay3=q2.z; az3=q2.w;
    }
    float m0=3.4028235e38f, m1=3.4028235e38f, m2=3.4028235e38f, m3=3.4028235e38f;

    __syncthreads();

    #pragma unroll 4
    for (int j = 0; j < 512; ++j) {
        const float bx = lds[3*j+0];   // same addr across wave -> LDS broadcast
        const float by = lds[3*j+1];
        const float bz = lds[3*j+2];
        float dx, dy, dz, d;
        dx=ax0-bx; dy=ay0-by; dz=az0-bz; d=dx*dx+dy*dy+dz*dz; m0=fminf(m0,d);
        dx=ax1-bx; dy=ay1-by; dz=az1-bz; d=dx*dx+dy*dy+dz*dz; m1=fminf(m1,d);
        dx=ax2-bx; dy=ay2-by; dz=az2-bz; d=dx*dx+dy*dy+dz*dz; m2=fminf(m2,d);
        dx=ax3-bx; dy=ay3-by; dz=az3-bz; d=dx*dx+dy*dy+dz*dz; m3=fminf(m3,d);
    }

    // Nonnegative floats: uint bit order == float order, so atomicMin on bits
    // computes the float min across the 16 b-chunks.
    atomicMin(o + pbase + 0, __float_as_uint(m0));
    atomicMin(o + pbase + 1, __float_as_uint(m1));
    atomicMin(o + pbase + 2, __float_as_uint(m2));
    atomicMin(o + pbase + 3, __float_as_uint(m3));
}

extern "C" void kernel_launch(void* const* d_in, const int* in_sizes, int n_in,
                              void* d_out, int out_size, void* d_ws, size_t ws_size,
                              hipStream_t stream) {
    const float* x = (const float*)d_in[0];
    const float* y = (const float*)d_in[1];
    unsigned int* out = (unsigned int*)d_out;

    // out_size = 2*2*8192 = 32768, divisible by 256
    _chamfer_init<<<dim3(out_size / 256), dim3(256), 0, stream>>>(out);

    // grid: 8 a-tiles x 2 batches x (2 dirs * 16 b-chunks) = 512 blocks
    _chamfer_min<<<dim3(8, 2, 32), dim3(256), 0, stream>>>(x, y, out);
}

// Round 3
// 78.825 us; speedup vs baseline: 1.2911x; 1.2911x over previous
//
#include <hip/hip_runtime.h>

#define NPTS 8192
#define NB 2
#define NPB 256                 // b-points per chunk (staged per block)
#define NCHUNK (NPTS / NPB)     // 32

// Init output to +FLT_MAX bits so uint atomicMin == float min (nonneg floats).
__global__ void _chamfer_init(unsigned int* __restrict__ o) {
    o[blockIdx.x * 256 + threadIdx.x] = 0x7F7FFFFFu;
}

// dir = z>>5 (0: a=x,b=y -> dl ; 1: a=y,b=x -> dr), chunk = z&31.
// Block: 1024 a-points (4/thread) x one 256-point b-chunk.
// Inner loop per pair: e_j = b2_j - 2 a.b_j  (3 FMA + 1 min);
// final d = max(a2 + min_j e_j, 0).
__global__ __launch_bounds__(256) void _chamfer_min(const float* __restrict__ x,
                                                    const float* __restrict__ y,
                                                    unsigned int* __restrict__ out) {
    const int atile = blockIdx.x;       // 0..7
    const int batch = blockIdx.y;       // 0..1
    const int dir   = blockIdx.z >> 5;  // 0..1
    const int chunk = blockIdx.z & 31;  // 0..31

    const float* a = dir ? y : x;
    const float* b = dir ? x : y;
    unsigned int* o = out + dir * (NB * NPTS) + batch * NPTS;

    __shared__ float4 lds[NPB];

    // Stage: thread t pre-transforms b-point t -> (-2bx, -2by, -2bz, |b|^2).
    {
        const float* bp = b + batch * NPTS * 3 + (chunk * NPB + (int)threadIdx.x) * 3;
        const float bx = bp[0], by = bp[1], bz = bp[2];
        lds[threadIdx.x] = make_float4(-2.f * bx, -2.f * by, -2.f * bz,
                                       bx * bx + by * by + bz * bz);
    }

    // Each thread owns 4 consecutive a-points: 12 floats = 3 aligned float4.
    const int pbase = atile * 1024 + (int)threadIdx.x * 4;
    float ax0,ay0,az0, ax1,ay1,az1, ax2,ay2,az2, ax3,ay3,az3;
    {
        const float4* asrc = (const float4*)(a + batch * NPTS * 3 + pbase * 3);
        float4 q0 = asrc[0], q1 = asrc[1], q2 = asrc[2];
        ax0=q0.x; ay0=q0.y; az0=q0.z;
        ax1=q0.w; ay1=q1.x; az1=q1.y;
        ax2=q1.z; ay2=q1.w; az2=q2.x;
        ax3=q2.y; ay3=q2.z; az3=q2.w;
    }
    const float a20 = ax0*ax0 + ay0*ay0 + az0*az0;
    const float a21 = ax1*ax1 + ay1*ay1 + az1*az1;
    const float a22 = ax2*ax2 + ay2*ay2 + az2*az2;
    const float a23 = ax3*ax3 + ay3*ay3 + az3*az3;

    float m0=3.4028235e38f, m1=3.4028235e38f, m2=3.4028235e38f, m3=3.4028235e38f;

    __syncthreads();

    #pragma unroll 8
    for (int j = 0; j < NPB; ++j) {
        const float4 bb = lds[j];   // uniform addr -> LDS broadcast, 1x ds_read_b128
        float e;
        e = fmaf(ax0, bb.x, fmaf(ay0, bb.y, fmaf(az0, bb.z, bb.w))); m0 = fminf(m0, e);
        e = fmaf(ax1, bb.x, fmaf(ay1, bb.y, fmaf(az1, bb.z, bb.w))); m1 = fminf(m1, e);
        e = fmaf(ax2, bb.x, fmaf(ay2, bb.y, fmaf(az2, bb.z, bb.w))); m2 = fminf(m2, e);
        e = fmaf(ax3, bb.x, fmaf(ay3, bb.y, fmaf(az3, bb.z, bb.w))); m3 = fminf(m3, e);
    }

    // d = max(a2 + min_e, 0): clamp is monotone, so per-chunk clamp + atomicMin
    // over chunks == clamp of global min. Result >= 0 -> uint bit order valid.
    m0 = fmaxf(a20 + m0, 0.f);
    m1 = fmaxf(a21 + m1, 0.f);
    m2 = fmaxf(a22 + m2, 0.f);
    m3 = fmaxf(a23 + m3, 0.f);

    atomicMin(o + pbase + 0, __float_as_uint(m0));
    atomicMin(o + pbase + 1, __float_as_uint(m1));
    atomicMin(o + pbase + 2, __float_as_uint(m2));
    atomicMin(o + pbase + 3, __float_as_uint(m3));
}

extern "C" void kernel_launch(void* const* d_in, const int* in_sizes, int n_in,
                              void* d_out, int out_size, void* d_ws, size_t ws_size,
                              hipStream_t stream) {
    const float* x = (const float*)d_in[0];
    const float* y = (const float*)d_in[1];
    unsigned int* out = (unsigned int*)d_out;

    _chamfer_init<<<dim3(out_size / 256), dim3(256), 0, stream>>>(out);

    // 8 a-tiles x 2 batches x (2 dirs * 32 chunks) = 1024 blocks -> 4 blocks/CU
    _chamfer_min<<<dim3(8, 2, 64), dim3(256), 0, stream>>>(x, y, out);
}